// Round 22
// baseline (107.940 us; speedup 1.0000x reference)
//
#include <hip/hip_runtime.h>
#include <hip/hip_fp16.h>
#include <math.h>

#define P 128
#define NP (P*P)
#define BATCH 4

typedef __attribute__((ext_vector_type(8))) short bf16x8;
typedef __attribute__((ext_vector_type(4))) short s16x4;
typedef __attribute__((ext_vector_type(8))) _Float16 h16x8;
typedef __attribute__((ext_vector_type(4))) float f32x4;

__device__ __forceinline__ float sigmoidf_(float x){ return 1.f/(1.f+__expf(-x)); }
__device__ __forceinline__ float tanhf_(float x){
  float ax = fabsf(x);
  float e = __expf(2.f*ax);
  float t = 1.f - 2.f/(e + 1.f);
  return copysignf(t, x);
}
__device__ __forceinline__ short f2bf(float f){
  unsigned u = __builtin_bit_cast(unsigned, f);
  u = (u + 0x7FFFu + ((u>>16)&1u)) >> 16;
  return (short)u;
}
__device__ __forceinline__ float bf2f(short s){
  unsigned u = ((unsigned)(unsigned short)s) << 16;
  return __builtin_bit_cast(float, u);
}
__device__ __forceinline__ short f2h(float f){
  return (short)__half_as_short(__float2half(f));
}
// packed fp16 relu on a 2-half vector (sign-bit select, branch-free)
__device__ __forceinline__ __half2 relu2_(__half2 v){
  unsigned u = __builtin_bit_cast(unsigned, v);
  unsigned m = ((u & 0x80000000u) ? 0u : 0xFFFF0000u) | ((u & 0x8000u) ? 0u : 0xFFFFu);
  return __builtin_bit_cast(__half2, u & m);
}

// ---------------- merged: maxpool->fp16 (256) + h0 transpose->fp16 (1024) + weight prep (1476) ----------------
// gates wA (fp16): [tap9][cb4][mb16][lane64][s8]; chunk c=tap*4+cb contiguous 16KB.
__global__ void prep_k(const float* __restrict__ x, short* __restrict__ xph,
                       const float* __restrict__ h0, short* __restrict__ hcl,
                       const float* __restrict__ wg, const float* __restrict__ w1,
                       const float* __restrict__ w2, const float* __restrict__ wo1,
                       const float* __restrict__ wo2,
                       short* __restrict__ wA, short* __restrict__ wd1T,
                       short* __restrict__ wd2T, short* __restrict__ woT1,
                       short* __restrict__ woT2){
  int bx = blockIdx.x;
  int tid = threadIdx.x;
  if (bx < 256){
    int idx = bx*256 + tid;
    int wp = idx & (P-1); int t = idx >> 7; int hp = t & (P-1); int b = t >> 7;
    const float* src = x + ((size_t)b*32*65536) + (size_t)(hp*2)*256 + wp*2;
    float m[32];
    #pragma unroll
    for (int c = 0; c < 32; c++){
      const float* s = src + (size_t)c*65536;
      float2 t0 = *(const float2*)s;
      float2 t1 = *(const float2*)(s + 256);
      m[c] = fmaxf(fmaxf(t0.x, t0.y), fmaxf(t1.x, t1.y));
    }
    union { __half2 h[16]; h16x8 v[4]; } o;
    #pragma unroll
    for (int j = 0; j < 16; j++) o.h[j] = __float22half2_rn(float2{m[2*j], m[2*j+1]});
    short* dst = xph + (size_t)idx*32;
    #pragma unroll
    for (int q = 0; q < 4; q++) *(h16x8*)(dst + q*8) = o.v[q];
    return;
  }
  if (bx < 1280){
    __shared__ float t[64][65];
    int blk = bx - 256;
    int b = blk >> 8;
    int p0 = (blk & 255)*64;
    int pl = tid & 63;
    int cq = tid >> 6;
    const float* src = h0 + (size_t)b*64*NP + p0 + pl;
    #pragma unroll
    for (int i = 0; i < 16; i++)
      t[cq*16+i][pl] = src[(size_t)(cq*16+i)*NP];
    __syncthreads();
    int p = tid >> 2, q = tid & 3;
    short* dst = hcl + ((size_t)(b*NP + p0 + p))*64 + q*16;
    union { short s[8]; bf16x8 v; } o0, o1;
    #pragma unroll
    for (int i = 0; i < 8; i++){ o0.s[i] = f2h(t[q*16+i][p]); o1.s[i] = f2h(t[q*16+8+i][p]); }
    *(bf16x8*)dst = o0.v;
    *(bf16x8*)(dst+8) = o1.v;
    return;
  }
  int idx = (bx - 1280)*256 + tid;
  if (idx < 294912){
    int s = idx & 7; int l = (idx>>3) & 63; int mb = (idx>>9) & 15;
    int cb = (idx>>13) & 3; int tap = idx >> 15;
    int ln = l & 15, kg = l >> 4;
    int r = mb*16 + ln; int ch = r >> 2, gate = r & 3;
    int cin = cb*32 + kg*8 + s;
    wA[idx] = f2h(wg[((size_t)(gate*64 + ch)*128 + cin)*9 + tap]);
    return;
  }
  idx -= 294912;
  if (idx < 18432){
    int s = idx & 7; int l = (idx>>3) & 63; int mb = (idx>>9) & 3; int tap = idx >> 11;
    int ln = l & 15, kg = l >> 4;
    int o = mb*16 + ln; int cin = kg*8 + s;
    wd1T[idx] = f2h(w1[((size_t)(o*32 + cin))*9 + tap]);
    return;
  }
  idx -= 18432;
  if (idx < 36864){
    int s = idx & 7; int l = (idx>>3) & 63; int mb = (idx>>9) & 3;
    int cb = (idx>>11) & 1; int tap = idx >> 12;
    int ln = l & 15, kg = l >> 4;
    int o = mb*16 + ln; int cin = cb*32 + kg*8 + s;
    wd2T[idx] = f2h(w2[((size_t)(o*64 + cin))*9 + tap]);
    return;
  }
  idx -= 36864;
  if (idx < 9216){
    int s = idx & 7; int l = (idx>>3) & 63; int mb = (idx>>9) & 1; int tap = idx >> 10;
    int ln = l & 15, kg = l >> 4;
    int o = mb*16 + ln; int cin = kg*8 + s;
    woT1[idx] = (o < 18) ? f2h(wo1[((size_t)(o*32 + cin))*9 + tap]) : (short)0;
    return;
  }
  idx -= 9216;
  if (idx < 18432){
    int s = idx & 7; int l = (idx>>3) & 63; int mb = (idx>>9) & 1;
    int cb = (idx>>10) & 1; int tap = idx >> 11;
    int ln = l & 15, kg = l >> 4;
    int o = mb*16 + ln; int cin = cb*32 + kg*8 + s;
    woT2[idx] = (o < 18) ? f2h(wo2[((size_t)(o*64 + cin))*9 + tap]) : (short)0;
  }
}

// ---------------- fused offset-conv + deformable conv (fp16 MFMA) + BN partial sums ----------------
// 16x8 px tile, halo 22x14; 4 waves x 2 rows. Input fp16 channels-last (raw if !BNIN).
// Output fp16 channels-last + fp32 BN partials (from fp32 acc).
template<int CIN, bool BNIN>
__global__ __launch_bounds__(256) void deform_fused_k(
    const short* __restrict__ incl, const float* __restrict__ bstats,
    const float* __restrict__ b_off,
    const short* __restrict__ woT, const short* __restrict__ wdT,
    short* __restrict__ outb, float* __restrict__ part){
  const int HSX = 22, HSY = 14, NHP = HSX*HSY;   // 308
  const int ROWB = CIN*2;
  const int CG = CIN/8, CGS = (CIN==64)?3:2;
  const int PM = (CIN==64)?7:3;
  const int NCB = CIN/32;
  __shared__ short xt[NHP*CIN];
  __shared__ float off_lds[128][20];
  __shared__ float red_s[4][64], red_q[4][64];
  int tid = threadIdx.x;
  int tile = blockIdx.x, b = blockIdx.y;
  int tx0 = (tile & 7)*16, ty0 = (tile >> 3)*8;
  // ---- phase 1: stage halo -> fp16 LDS (swizzled)
  for (int e = tid; e < NHP*CG; e += 256){
    int cg = e & (CG-1), p = e >> CGS;
    int hr = p/HSX, wc = p - hr*HSX;
    int gy = ty0 + hr - 3, gx = tx0 + wc - 3;
    union { short s[8]; __half2 h[4]; h16x8 v; } u;
    bool ok = ((unsigned)gy < P) && ((unsigned)gx < P);
    if (ok){
      const short* src = incl + ((size_t)b*NP + (size_t)gy*P + gx)*CIN + cg*8;
      if constexpr (!BNIN){
        u.v = *(const h16x8*)(const void*)src;
      } else {
        h16x8 raw = *(const h16x8*)(const void*)src;
        float v[8];
        #pragma unroll
        for (int j = 0; j < 8; j++) v[j] = (float)raw[j];
        int c = cg*8;
        #pragma unroll
        for (int j = 0; j < 8; j++) v[j] = fmaxf(v[j]*bstats[c+j]+bstats[64+c+j], 0.f);
        u.h[0] = __float22half2_rn(float2{v[0], v[1]});
        u.h[1] = __float22half2_rn(float2{v[2], v[3]});
        u.h[2] = __float22half2_rn(float2{v[4], v[5]});
        u.h[3] = __float22half2_rn(float2{v[6], v[7]});
      }
    } else {
      #pragma unroll
      for (int j = 0; j < 8; j++) u.s[j] = 0;
    }
    *(h16x8*)((char*)xt + p*ROWB + ((cg*16) ^ ((p & PM)<<4))) = u.v;
  }
  __syncthreads();

  int lane = tid & 63, wid = tid >> 6;
  int kg = lane >> 4, ln = lane & 15;
  int pxg = tx0 + ln;

  // ---- phase 2: offset conv (M=32, 18 real) for this wave's 32 px (2 rows)
  {
    f32x4 acc_o[2][2];
    #pragma unroll
    for (int mf = 0; mf < 2; mf++)
      #pragma unroll
      for (int nf = 0; nf < 2; nf++) acc_o[mf][nf] = (f32x4){0.f,0.f,0.f,0.f};
    #pragma unroll
    for (int tap = 0; tap < 9; tap++){
      int ky = tap/3, kx = tap - (tap/3)*3;
      #pragma unroll
      for (int nf = 0; nf < 2; nf++){
        int p = (wid*2 + nf + ky + 2)*HSX + (ln + kx + 2);
        #pragma unroll
        for (int cb = 0; cb < NCB; cb++){
          h16x8 bfv = *(const h16x8*)((const char*)xt + p*ROWB + (((cb*64) + kg*16) ^ ((p & PM)<<4)));
          h16x8 af0 = *(const h16x8*)(const void*)(woT + ((size_t)((tap*NCB + cb)*2 + 0)*512 + lane*8));
          h16x8 af1 = *(const h16x8*)(const void*)(woT + ((size_t)((tap*NCB + cb)*2 + 1)*512 + lane*8));
          acc_o[0][nf] = __builtin_amdgcn_mfma_f32_16x16x32_f16(af0, bfv, acc_o[0][nf], 0, 0, 0);
          acc_o[1][nf] = __builtin_amdgcn_mfma_f32_16x16x32_f16(af1, bfv, acc_o[1][nf], 0, 0, 0);
        }
      }
    }
    #pragma unroll
    for (int nf = 0; nf < 2; nf++){
      int pl = wid*32 + nf*16 + ln;
      #pragma unroll
      for (int mf = 0; mf < 2; mf++){
        #pragma unroll
        for (int j = 0; j < 4; j++){
          int o = mf*16 + kg*4 + j;
          if (o < 18) off_lds[pl][o] = acc_o[mf][nf][j] + b_off[o];
        }
      }
    }
  }
  __syncthreads();

  // ---- phase 3: bilinear sample (2 px/lane) + fp16 MFMA
  f32x4 acc[4][2];
  #pragma unroll
  for (int mf = 0; mf < 4; mf++)
    #pragma unroll
    for (int nf = 0; nf < 2; nf++) acc[mf][nf] = (f32x4){0.f,0.f,0.f,0.f};

  for (int tap = 0; tap < 9; tap++){
    __half2 w00h[2], w01h[2], w10h[2], w11h[2];
    int p00[2], p01[2], p10[2], p11[2];
    #pragma unroll
    for (int nf = 0; nf < 2; nf++){
      int pl = wid*32 + nf*16 + ln;
      int py = ty0 + wid*2 + nf;
      float dy = off_lds[pl][tap], dx = off_lds[pl][9+tap];
      float ys = (float)(py + tap/3 - 1) + dy;
      float xs = (float)(pxg + tap%3 - 1) + dx;
      float y0f = floorf(ys), x0f = floorf(xs);
      float wy1 = ys - y0f, wx1 = xs - x0f;
      float wy0 = 1.f - wy1, wx0 = 1.f - wx1;
      int y0 = (int)y0f, x0 = (int)x0f;
      bool v0y = ((unsigned)y0 < P), v1y = ((unsigned)(y0+1) < P);
      bool v0x = ((unsigned)x0 < P), v1x = ((unsigned)(x0+1) < P);
      w00h[nf] = __float2half2_rn((v0y && v0x) ? wy0*wx0 : 0.f);
      w01h[nf] = __float2half2_rn((v0y && v1x) ? wy0*wx1 : 0.f);
      w10h[nf] = __float2half2_rn((v1y && v0x) ? wy1*wx0 : 0.f);
      w11h[nf] = __float2half2_rn((v1y && v1x) ? wy1*wx1 : 0.f);
      int ly0 = min(max(y0 - ty0 + 3, 0), HSY-1);
      int ly1 = min(max(y0 + 1 - ty0 + 3, 0), HSY-1);
      int lx0 = min(max(x0 - tx0 + 3, 0), HSX-1);
      int lx1 = min(max(x0 + 1 - tx0 + 3, 0), HSX-1);
      p00[nf] = ly0*HSX + lx0; p01[nf] = ly0*HSX + lx1;
      p10[nf] = ly1*HSX + lx0; p11[nf] = ly1*HSX + lx1;
    }
    #pragma unroll
    for (int cb = 0; cb < NCB; cb++){
      int ko = (cb*32 + kg*8)*2;
      h16x8 af[4];
      #pragma unroll
      for (int mf = 0; mf < 4; mf++)
        af[mf] = *(const h16x8*)(const void*)(wdT + ((size_t)((tap*NCB + cb)*4 + mf)*512 + lane*8));
      #pragma unroll
      for (int nf = 0; nf < 2; nf++){
        union { __half2 h[4]; h16x8 v; } c00, c01, c10, c11, bu;
        c00.v = *(const h16x8*)((const char*)xt + p00[nf]*ROWB + (ko ^ ((p00[nf] & PM)<<4)));
        c01.v = *(const h16x8*)((const char*)xt + p01[nf]*ROWB + (ko ^ ((p01[nf] & PM)<<4)));
        c10.v = *(const h16x8*)((const char*)xt + p10[nf]*ROWB + (ko ^ ((p10[nf] & PM)<<4)));
        c11.v = *(const h16x8*)((const char*)xt + p11[nf]*ROWB + (ko ^ ((p11[nf] & PM)<<4)));
        #pragma unroll
        for (int j = 0; j < 4; j++){
          bu.h[j] = __hfma2(c00.h[j], w00h[nf],
                    __hfma2(c01.h[j], w01h[nf],
                    __hfma2(c10.h[j], w10h[nf],
                    __hmul2(c11.h[j], w11h[nf]))));
        }
        #pragma unroll
        for (int mf = 0; mf < 4; mf++)
          acc[mf][nf] = __builtin_amdgcn_mfma_f32_16x16x32_f16(af[mf], bu.v, acc[mf][nf], 0, 0, 0);
      }
    }
  }
  // epilogue: fp16 channels-last stores (2 px/lane)
  #pragma unroll
  for (int nf = 0; nf < 2; nf++){
    int py = ty0 + wid*2 + nf;
    #pragma unroll
    for (int mf = 0; mf < 4; mf++){
      short* dst = outb + ((size_t)b*NP + (size_t)py*P + pxg)*64 + mf*16 + kg*4;
      s16x4 o;
      #pragma unroll
      for (int j = 0; j < 4; j++) o[j] = f2h(acc[mf][nf][j]);
      *(s16x4*)dst = o;
    }
  }

  // BN partial sums from fp32 acc (both pixels)
  #pragma unroll
  for (int mf = 0; mf < 4; mf++){
    #pragma unroll
    for (int j = 0; j < 4; j++){
      float a0 = acc[mf][0][j], a1 = acc[mf][1][j];
      float s = a0 + a1, q = a0*a0 + a1*a1;
      #pragma unroll
      for (int o = 1; o < 16; o <<= 1){
        s += __shfl_xor(s, o);
        q += __shfl_xor(q, o);
      }
      if (ln == 0){
        int ch = mf*16 + kg*4 + j;
        red_s[wid][ch] = s;
        red_q[wid][ch] = q;
      }
    }
  }
  __syncthreads();
  int blk = b*128 + tile;
  if (tid < 128){
    int ch = tid & 63;
    float v = (tid < 64)
      ? (red_s[0][ch]+red_s[1][ch]+red_s[2][ch]+red_s[3][ch])
      : (red_q[0][ch]+red_q[1][ch]+red_q[2][ch]+red_q[3][ch]);
    part[(size_t)tid*512 + blk] = v;
  }
}

// ---------------- BN finalize (512 partials per channel) ----------------
__global__ void bnfinal2_k(const float* __restrict__ part, const float* __restrict__ g,
                           const float* __restrict__ be, float* __restrict__ stats){
  int ch = blockIdx.x;
  int tid = threadIdx.x;
  float S = 0.f, Q = 0.f;
  for (int i = tid; i < 512; i += 256){
    S += part[(size_t)ch*512 + i];
    Q += part[(size_t)(64+ch)*512 + i];
  }
  __shared__ float rs[256], rq[256];
  rs[tid] = S; rq[tid] = Q;
  __syncthreads();
  for (int o = 128; o > 0; o >>= 1){
    if (tid < o){ rs[tid] += rs[tid+o]; rq[tid] += rq[tid+o]; }
    __syncthreads();
  }
  if (tid == 0){
    const float inv = 1.f/(float)(BATCH*NP);
    float mean = rs[0]*inv;
    float var = rq[0]*inv - mean*mean;
    float scale = rsqrtf(var + 1e-5f)*g[ch];
    stats[ch] = scale;
    stats[64+ch] = be[ch] - mean*scale;
  }
}

// ---------------- gates conv (128->256) fp16 MFMA + fused BN2 (packed) + LSTM ----------------
__global__ __launch_bounds__(512, 4) void gates_mfma_k(
    const short* __restrict__ y2h, const float* __restrict__ stats,
    const short* __restrict__ hcl, const float* __restrict__ c0,
    const short* __restrict__ wA, const float* __restrict__ bg,
    float* __restrict__ outh, float* __restrict__ outc){
  extern __shared__ short lds[];
  short* bs = lds;                  // 180 px x 256B (swizzled) = 46080 B
  short* abuf = lds + 180*128;      // 2 x 8192 shorts (16 KB each)
  __shared__ short hst[128];        // fp16 scale[0:64], shift[64:128]
  int tid = threadIdx.x;
  int tile = blockIdx.x, b = blockIdx.y;
  int tx0 = (tile & 7)*16, ty0 = (tile >> 3)*8;
  int lane = tid & 63, wid = tid >> 6;

  if (tid < 128) hst[tid] = f2h(stats[tid]);
  __syncthreads();

  for (int e = tid; e < 180*16; e += 512){
    int cg = e & 15, p = e >> 4;
    int hr = p/18, wc = p - hr*18;
    int gy = ty0 + hr - 1, gx = tx0 + wc - 1;
    union { short s[8]; __half2 h[4]; h16x8 v; } u;
    if (((unsigned)gy < P) && ((unsigned)gx < P)){
      if (cg < 8){
        const short* src = y2h + ((size_t)(b*NP) + (size_t)gy*P + gx)*64 + cg*8;
        union { __half2 h[4]; h16x8 v; } r;
        r.v = *(const h16x8*)(const void*)src;
        int c = cg*8;
        const __half2* sc2 = (const __half2*)(const void*)(hst + c);
        const __half2* sh2 = (const __half2*)(const void*)(hst + 64 + c);
        #pragma unroll
        for (int j = 0; j < 4; j++)
          u.h[j] = relu2_(__hfma2(r.h[j], sc2[j], sh2[j]));
      } else {
        u.v = *(const h16x8*)(const void*)(hcl + ((size_t)(b*NP) + (size_t)gy*P + gx)*64 + (cg-8)*8);
      }
    } else {
      #pragma unroll
      for (int j = 0; j < 8; j++) u.s[j] = 0;
    }
    *(h16x8*)((char*)bs + p*256 + ((cg*16) ^ ((p&7)<<4))) = u.v;
  }

  auto stageA = [&](int c, int bi){
    const short* g = wA + (size_t)c*8192;
    short* l = abuf + bi*8192;
    #pragma unroll
    for (int i = 0; i < 2; i++){
      int unit = wid*2 + i;
      __builtin_amdgcn_global_load_lds(
          (const __attribute__((address_space(1))) unsigned int*)(g + (size_t)(unit*64 + lane)*8),
          (__attribute__((address_space(3))) unsigned int*)(l + (size_t)unit*512),
          16, 0, 0);
    }
  };

  stageA(0, 0);
  stageA(1, 1);
  __syncthreads();   // B staged + chunks 0,1 landed

  int kg = lane >> 4, ln = lane & 15;
  int ct = wid >> 1, nh = wid & 1;
  f32x4 acc[4][4];
  #pragma unroll
  for (int mf = 0; mf < 4; mf++)
    #pragma unroll
    for (int rr = 0; rr < 4; rr++) acc[mf][rr] = (f32x4){0.f,0.f,0.f,0.f};

  for (int c = 0; c < 36; c++){
    int cur = c & 1;
    int tap = c >> 2, cb = c & 3;
    int ky = tap/3, kx = tap - ky*3;
    const short* al = abuf + cur*8192;
    h16x8 af[4], bf[4];
    #pragma unroll
    for (int mf = 0; mf < 4; mf++)
      af[mf] = *(const h16x8*)(const void*)(al + (size_t)(ct*4 + mf)*512 + lane*8);
    #pragma unroll
    for (int rr = 0; rr < 4; rr++){
      int p = (nh*4 + rr + ky)*18 + ln + kx;
      bf[rr] = *(const h16x8*)((const char*)bs + p*256 + (((cb*64) + kg*16) ^ ((p&7)<<4)));
    }
    asm volatile("s_waitcnt lgkmcnt(0)" ::: "memory");
    __builtin_amdgcn_sched_barrier(0);
    __builtin_amdgcn_s_setprio(1);
    #pragma unroll
    for (int rr = 0; rr < 4; rr++)
      #pragma unroll
      for (int mf = 0; mf < 4; mf++)
        acc[mf][rr] = __builtin_amdgcn_mfma_f32_16x16x32_f16(af[mf], bf[rr], acc[mf][rr], 0, 0, 0);
    __builtin_amdgcn_s_setprio(0);
    asm volatile("s_waitcnt vmcnt(0)" ::: "memory");
    __builtin_amdgcn_sched_barrier(0);
    __builtin_amdgcn_s_barrier();
    __builtin_amdgcn_sched_barrier(0);
    if (c + 2 < 36) stageA(c + 2, cur);   // overlaps next iter's ds_read + MFMA
  }

  #pragma unroll
  for (int mf = 0; mf < 4; mf++){
    int ch = ct*16 + mf*4 + kg;
    float bi = bg[ch], bff = bg[64+ch], bo = bg[128+ch], bgv = bg[192+ch];
    #pragma unroll
    for (int rr = 0; rr < 4; rr++){
      int py = ty0 + nh*4 + rr, px = tx0 + ln;
      size_t pidx = ((size_t)(b*64 + ch))*NP + (size_t)py*P + px;
      f32x4 a = acc[mf][rr];
      float cv = sigmoidf_(a[1]+bff)*c0[pidx] + sigmoidf_(a[0]+bi)*tanhf_(a[3]+bgv);
      float hv = sigmoidf_(a[2]+bo)*tanhf_(cv);
      outh[pidx] = hv;
      outc[pidx] = cv;
    }
  }
}

extern "C" void kernel_launch(void* const* d_in, const int* in_sizes, int n_in,
                              void* d_out, int out_size, void* d_ws, size_t ws_size,
                              hipStream_t stream) {
  const float* x      = (const float*)d_in[0];
  const float* h0     = (const float*)d_in[1];
  const float* c0     = (const float*)d_in[2];
  const float* w_off1 = (const float*)d_in[3];
  const float* b_off1 = (const float*)d_in[4];
  const float* w1     = (const float*)d_in[5];
  const float* g1     = (const float*)d_in[6];
  const float* be1    = (const float*)d_in[7];
  const float* w_off2 = (const float*)d_in[8];
  const float* b_off2 = (const float*)d_in[9];
  const float* w2     = (const float*)d_in[10];
  const float* g2     = (const float*)d_in[11];
  const float* be2    = (const float*)d_in[12];
  const float* wg     = (const float*)d_in[13];
  const float* bg     = (const float*)d_in[14];

  float* ws     = (float*)d_ws;
  short* xph    = (short*)ws;                  // fp16, 2097152 shorts
  short* hcl    = (short*)(ws + 1048576);      // fp16, 4194304 shorts
  short* y1h    = (short*)(ws + 3145728);      // fp16, 4194304 shorts
  short* y2h    = (short*)(ws + 5242880);      // fp16, 4194304 shorts
  float* part   = ws + 7340032;                // 65536
  float* stats1 = ws + 7405568;                // 128
  float* stats2 = ws + 7405696;                // 128
  short* wA     = (short*)(ws + 7405824);      // 294912 shorts (fp16)
  short* wd1T   = wA + 294912;                 // 18432
  short* wd2T   = wd1T + 18432;                // 36864
  short* woT1   = wd2T + 36864;                // 9216
  short* woT2   = woT1 + 9216;                 // 18432

  (void)hipFuncSetAttribute((const void*)gates_mfma_k,
                            hipFuncAttributeMaxDynamicSharedMemorySize, 78848);

  prep_k<<<dim3(256 + 1024 + 1476), dim3(256), 0, stream>>>(
      x, xph, h0, hcl, wg, w1, w2, w_off1, w_off2, wA, wd1T, wd2T, woT1, woT2);

  deform_fused_k<32,false><<<dim3(128, BATCH), dim3(256), 0, stream>>>(
      xph, stats1, b_off1, woT1, wd1T, y1h, part);
  bnfinal2_k<<<dim3(64), dim3(256), 0, stream>>>(part, g1, be1, stats1);

  deform_fused_k<64,true><<<dim3(128, BATCH), dim3(256), 0, stream>>>(
      y1h, stats1, b_off2, woT2, wd2T, y2h, part);
  bnfinal2_k<<<dim3(64), dim3(256), 0, stream>>>(part, g2, be2, stats2);

  float* outh = (float*)d_out;
  float* outc = outh + (size_t)BATCH*64*NP;
  gates_mfma_k<<<dim3(128, BATCH), dim3(512), 78848, stream>>>(
      y2h, stats2, hcl, c0, wA, bg, outh, outc);
}

// Round 23
// 106.039 us; speedup vs baseline: 1.0179x; 1.0179x over previous
//
#include <hip/hip_runtime.h>
#include <hip/hip_fp16.h>
#include <math.h>

#define P 128
#define NP (P*P)
#define BATCH 4

typedef __attribute__((ext_vector_type(8))) short bf16x8;
typedef __attribute__((ext_vector_type(4))) short s16x4;
typedef __attribute__((ext_vector_type(8))) _Float16 h16x8;
typedef __attribute__((ext_vector_type(4))) float f32x4;

__device__ __forceinline__ float sigmoidf_(float x){ return 1.f/(1.f+__expf(-x)); }
__device__ __forceinline__ float tanhf_(float x){
  float ax = fabsf(x);
  float e = __expf(2.f*ax);
  float t = 1.f - 2.f/(e + 1.f);
  return copysignf(t, x);
}
__device__ __forceinline__ short f2bf(float f){
  unsigned u = __builtin_bit_cast(unsigned, f);
  u = (u + 0x7FFFu + ((u>>16)&1u)) >> 16;
  return (short)u;
}
__device__ __forceinline__ float bf2f(short s){
  unsigned u = ((unsigned)(unsigned short)s) << 16;
  return __builtin_bit_cast(float, u);
}
__device__ __forceinline__ short f2h(float f){
  return (short)__half_as_short(__float2half(f));
}

// ---------------- merged: maxpool->fp16 (256) + h0 transpose->bf16 (1024) + weight prep (1476) ----------------
// gates wA (bf16): [tap9][cb4][mb16][lane64][s8]; chunk c=tap*4+cb contiguous 16KB.
__global__ void prep_k(const float* __restrict__ x, short* __restrict__ xph,
                       const float* __restrict__ h0, short* __restrict__ hcl,
                       const float* __restrict__ wg, const float* __restrict__ w1,
                       const float* __restrict__ w2, const float* __restrict__ wo1,
                       const float* __restrict__ wo2,
                       short* __restrict__ wA, short* __restrict__ wd1T,
                       short* __restrict__ wd2T, short* __restrict__ woT1,
                       short* __restrict__ woT2){
  int bx = blockIdx.x;
  int tid = threadIdx.x;
  if (bx < 256){
    int idx = bx*256 + tid;
    int wp = idx & (P-1); int t = idx >> 7; int hp = t & (P-1); int b = t >> 7;
    const float* src = x + ((size_t)b*32*65536) + (size_t)(hp*2)*256 + wp*2;
    float m[32];
    #pragma unroll
    for (int c = 0; c < 32; c++){
      const float* s = src + (size_t)c*65536;
      float2 t0 = *(const float2*)s;
      float2 t1 = *(const float2*)(s + 256);
      m[c] = fmaxf(fmaxf(t0.x, t0.y), fmaxf(t1.x, t1.y));
    }
    union { __half2 h[16]; h16x8 v[4]; } o;
    #pragma unroll
    for (int j = 0; j < 16; j++) o.h[j] = __float22half2_rn(float2{m[2*j], m[2*j+1]});
    short* dst = xph + (size_t)idx*32;
    #pragma unroll
    for (int q = 0; q < 4; q++) *(h16x8*)(dst + q*8) = o.v[q];
    return;
  }
  if (bx < 1280){
    __shared__ float t[64][65];
    int blk = bx - 256;
    int b = blk >> 8;
    int p0 = (blk & 255)*64;
    int pl = tid & 63;
    int cq = tid >> 6;
    const float* src = h0 + (size_t)b*64*NP + p0 + pl;
    #pragma unroll
    for (int i = 0; i < 16; i++)
      t[cq*16+i][pl] = src[(size_t)(cq*16+i)*NP];
    __syncthreads();
    int p = tid >> 2, q = tid & 3;
    short* dst = hcl + ((size_t)(b*NP + p0 + p))*64 + q*16;
    union { short s[8]; bf16x8 v; } o0, o1;
    #pragma unroll
    for (int i = 0; i < 8; i++){ o0.s[i] = f2bf(t[q*16+i][p]); o1.s[i] = f2bf(t[q*16+8+i][p]); }
    *(bf16x8*)dst = o0.v;
    *(bf16x8*)(dst+8) = o1.v;
    return;
  }
  int idx = (bx - 1280)*256 + tid;
  if (idx < 294912){
    int s = idx & 7; int l = (idx>>3) & 63; int mb = (idx>>9) & 15;
    int cb = (idx>>13) & 3; int tap = idx >> 15;
    int ln = l & 15, kg = l >> 4;
    int r = mb*16 + ln; int ch = r >> 2, gate = r & 3;
    int cin = cb*32 + kg*8 + s;
    wA[idx] = f2bf(wg[((size_t)(gate*64 + ch)*128 + cin)*9 + tap]);
    return;
  }
  idx -= 294912;
  if (idx < 18432){
    int s = idx & 7; int l = (idx>>3) & 63; int mb = (idx>>9) & 3; int tap = idx >> 11;
    int ln = l & 15, kg = l >> 4;
    int o = mb*16 + ln; int cin = kg*8 + s;
    wd1T[idx] = f2h(w1[((size_t)(o*32 + cin))*9 + tap]);
    return;
  }
  idx -= 18432;
  if (idx < 36864){
    int s = idx & 7; int l = (idx>>3) & 63; int mb = (idx>>9) & 3;
    int cb = (idx>>11) & 1; int tap = idx >> 12;
    int ln = l & 15, kg = l >> 4;
    int o = mb*16 + ln; int cin = cb*32 + kg*8 + s;
    wd2T[idx] = f2h(w2[((size_t)(o*64 + cin))*9 + tap]);
    return;
  }
  idx -= 36864;
  if (idx < 9216){
    int s = idx & 7; int l = (idx>>3) & 63; int mb = (idx>>9) & 1; int tap = idx >> 10;
    int ln = l & 15, kg = l >> 4;
    int o = mb*16 + ln; int cin = kg*8 + s;
    woT1[idx] = (o < 18) ? f2h(wo1[((size_t)(o*32 + cin))*9 + tap]) : (short)0;
    return;
  }
  idx -= 9216;
  if (idx < 18432){
    int s = idx & 7; int l = (idx>>3) & 63; int mb = (idx>>9) & 1;
    int cb = (idx>>10) & 1; int tap = idx >> 11;
    int ln = l & 15, kg = l >> 4;
    int o = mb*16 + ln; int cin = cb*32 + kg*8 + s;
    woT2[idx] = (o < 18) ? f2h(wo2[((size_t)(o*64 + cin))*9 + tap]) : (short)0;
  }
}

// ---------------- fused offset-conv + deformable conv (fp16 MFMA) + BN partial sums ----------------
// 16x8 px tile, halo 22x14; 4 waves x 2 rows.
// INFMT: 0=fp32, 1=bf16, 2=fp16 (raw copy if !BNIN). Output bf16 + fp32 BN partials.
template<int CIN, bool BNIN, int INFMT>
__global__ __launch_bounds__(256) void deform_fused_k(
    const void* __restrict__ incl, const float* __restrict__ bstats,
    const float* __restrict__ b_off,
    const short* __restrict__ woT, const short* __restrict__ wdT,
    short* __restrict__ outb, float* __restrict__ part){
  const int HSX = 22, HSY = 14, NHP = HSX*HSY;   // 308
  const int ROWB = CIN*2;
  const int CG = CIN/8, CGS = (CIN==64)?3:2;
  const int PM = (CIN==64)?7:3;
  const int NCB = CIN/32;
  __shared__ short xt[NHP*CIN];
  __shared__ float off_lds[128][20];
  __shared__ float red_s[4][64], red_q[4][64];
  int tid = threadIdx.x;
  int tile = blockIdx.x, b = blockIdx.y;
  int tx0 = (tile & 7)*16, ty0 = (tile >> 3)*8;
  // ---- phase 1: stage halo -> fp16 LDS (swizzled)
  for (int e = tid; e < NHP*CG; e += 256){
    int cg = e & (CG-1), p = e >> CGS;
    int hr = p/HSX, wc = p - hr*HSX;
    int gy = ty0 + hr - 3, gx = tx0 + wc - 3;
    union { short s[8]; __half2 h[4]; h16x8 v; } u;
    bool ok = ((unsigned)gy < P) && ((unsigned)gx < P);
    if (ok){
      if constexpr (INFMT == 2 && !BNIN){
        u.v = *(const h16x8*)((const short*)incl + ((size_t)b*NP + (size_t)gy*P + gx)*CIN + cg*8);
      } else {
        float v[8];
        if constexpr (INFMT == 1){
          const short* src = (const short*)incl + ((size_t)b*NP + (size_t)gy*P + gx)*CIN + cg*8;
          bf16x8 raw = *(const bf16x8*)src;
          #pragma unroll
          for (int j = 0; j < 8; j++) v[j] = bf2f(raw[j]);
        } else if constexpr (INFMT == 2){
          const short* src = (const short*)incl + ((size_t)b*NP + (size_t)gy*P + gx)*CIN + cg*8;
          h16x8 raw = *(const h16x8*)(const void*)src;
          #pragma unroll
          for (int j = 0; j < 8; j++) v[j] = (float)raw[j];
        } else {
          const float* src = (const float*)incl + ((size_t)b*NP + (size_t)gy*P + gx)*CIN + cg*8;
          float4 a = *(const float4*)src, bb = *(const float4*)(src+4);
          v[0]=a.x; v[1]=a.y; v[2]=a.z; v[3]=a.w;
          v[4]=bb.x; v[5]=bb.y; v[6]=bb.z; v[7]=bb.w;
        }
        if (BNIN){
          int c = cg*8;
          #pragma unroll
          for (int j = 0; j < 8; j++) v[j] = fmaxf(v[j]*bstats[c+j]+bstats[64+c+j], 0.f);
        }
        u.h[0] = __float22half2_rn(float2{v[0], v[1]});
        u.h[1] = __float22half2_rn(float2{v[2], v[3]});
        u.h[2] = __float22half2_rn(float2{v[4], v[5]});
        u.h[3] = __float22half2_rn(float2{v[6], v[7]});
      }
    } else {
      #pragma unroll
      for (int j = 0; j < 8; j++) u.s[j] = 0;
    }
    *(h16x8*)((char*)xt + p*ROWB + ((cg*16) ^ ((p & PM)<<4))) = u.v;
  }
  __syncthreads();

  int lane = tid & 63, wid = tid >> 6;
  int kg = lane >> 4, ln = lane & 15;
  int pxg = tx0 + ln;

  // ---- phase 2: offset conv (M=32, 18 real) for this wave's 32 px (2 rows)
  {
    f32x4 acc_o[2][2];
    #pragma unroll
    for (int mf = 0; mf < 2; mf++)
      #pragma unroll
      for (int nf = 0; nf < 2; nf++) acc_o[mf][nf] = (f32x4){0.f,0.f,0.f,0.f};
    #pragma unroll
    for (int tap = 0; tap < 9; tap++){
      int ky = tap/3, kx = tap - (tap/3)*3;
      #pragma unroll
      for (int nf = 0; nf < 2; nf++){
        int p = (wid*2 + nf + ky + 2)*HSX + (ln + kx + 2);
        #pragma unroll
        for (int cb = 0; cb < NCB; cb++){
          h16x8 bfv = *(const h16x8*)((const char*)xt + p*ROWB + (((cb*64) + kg*16) ^ ((p & PM)<<4)));
          h16x8 af0 = *(const h16x8*)(const void*)(woT + ((size_t)((tap*NCB + cb)*2 + 0)*512 + lane*8));
          h16x8 af1 = *(const h16x8*)(const void*)(woT + ((size_t)((tap*NCB + cb)*2 + 1)*512 + lane*8));
          acc_o[0][nf] = __builtin_amdgcn_mfma_f32_16x16x32_f16(af0, bfv, acc_o[0][nf], 0, 0, 0);
          acc_o[1][nf] = __builtin_amdgcn_mfma_f32_16x16x32_f16(af1, bfv, acc_o[1][nf], 0, 0, 0);
        }
      }
    }
    #pragma unroll
    for (int nf = 0; nf < 2; nf++){
      int pl = wid*32 + nf*16 + ln;
      #pragma unroll
      for (int mf = 0; mf < 2; mf++){
        #pragma unroll
        for (int j = 0; j < 4; j++){
          int o = mf*16 + kg*4 + j;
          if (o < 18) off_lds[pl][o] = acc_o[mf][nf][j] + b_off[o];
        }
      }
    }
  }
  __syncthreads();

  // ---- phase 3: bilinear sample (2 px/lane) + fp16 MFMA
  f32x4 acc[4][2];
  #pragma unroll
  for (int mf = 0; mf < 4; mf++)
    #pragma unroll
    for (int nf = 0; nf < 2; nf++) acc[mf][nf] = (f32x4){0.f,0.f,0.f,0.f};

  for (int tap = 0; tap < 9; tap++){
    __half2 w00h[2], w01h[2], w10h[2], w11h[2];
    int p00[2], p01[2], p10[2], p11[2];
    #pragma unroll
    for (int nf = 0; nf < 2; nf++){
      int pl = wid*32 + nf*16 + ln;
      int py = ty0 + wid*2 + nf;
      float dy = off_lds[pl][tap], dx = off_lds[pl][9+tap];
      float ys = (float)(py + tap/3 - 1) + dy;
      float xs = (float)(pxg + tap%3 - 1) + dx;
      float y0f = floorf(ys), x0f = floorf(xs);
      float wy1 = ys - y0f, wx1 = xs - x0f;
      float wy0 = 1.f - wy1, wx0 = 1.f - wx1;
      int y0 = (int)y0f, x0 = (int)x0f;
      bool v0y = ((unsigned)y0 < P), v1y = ((unsigned)(y0+1) < P);
      bool v0x = ((unsigned)x0 < P), v1x = ((unsigned)(x0+1) < P);
      w00h[nf] = __float2half2_rn((v0y && v0x) ? wy0*wx0 : 0.f);
      w01h[nf] = __float2half2_rn((v0y && v1x) ? wy0*wx1 : 0.f);
      w10h[nf] = __float2half2_rn((v1y && v0x) ? wy1*wx0 : 0.f);
      w11h[nf] = __float2half2_rn((v1y && v1x) ? wy1*wx1 : 0.f);
      int ly0 = min(max(y0 - ty0 + 3, 0), HSY-1);
      int ly1 = min(max(y0 + 1 - ty0 + 3, 0), HSY-1);
      int lx0 = min(max(x0 - tx0 + 3, 0), HSX-1);
      int lx1 = min(max(x0 + 1 - tx0 + 3, 0), HSX-1);
      p00[nf] = ly0*HSX + lx0; p01[nf] = ly0*HSX + lx1;
      p10[nf] = ly1*HSX + lx0; p11[nf] = ly1*HSX + lx1;
    }
    #pragma unroll
    for (int cb = 0; cb < NCB; cb++){
      int ko = (cb*32 + kg*8)*2;
      h16x8 af[4];
      #pragma unroll
      for (int mf = 0; mf < 4; mf++)
        af[mf] = *(const h16x8*)(const void*)(wdT + ((size_t)((tap*NCB + cb)*4 + mf)*512 + lane*8));
      #pragma unroll
      for (int nf = 0; nf < 2; nf++){
        union { __half2 h[4]; h16x8 v; } c00, c01, c10, c11, bu;
        c00.v = *(const h16x8*)((const char*)xt + p00[nf]*ROWB + (ko ^ ((p00[nf] & PM)<<4)));
        c01.v = *(const h16x8*)((const char*)xt + p01[nf]*ROWB + (ko ^ ((p01[nf] & PM)<<4)));
        c10.v = *(const h16x8*)((const char*)xt + p10[nf]*ROWB + (ko ^ ((p10[nf] & PM)<<4)));
        c11.v = *(const h16x8*)((const char*)xt + p11[nf]*ROWB + (ko ^ ((p11[nf] & PM)<<4)));
        #pragma unroll
        for (int j = 0; j < 4; j++){
          bu.h[j] = __hfma2(c00.h[j], w00h[nf],
                    __hfma2(c01.h[j], w01h[nf],
                    __hfma2(c10.h[j], w10h[nf],
                    __hmul2(c11.h[j], w11h[nf]))));
        }
        #pragma unroll
        for (int mf = 0; mf < 4; mf++)
          acc[mf][nf] = __builtin_amdgcn_mfma_f32_16x16x32_f16(af[mf], bu.v, acc[mf][nf], 0, 0, 0);
      }
    }
  }
  // epilogue: bf16 channels-last stores (2 px/lane)
  #pragma unroll
  for (int nf = 0; nf < 2; nf++){
    int py = ty0 + wid*2 + nf;
    #pragma unroll
    for (int mf = 0; mf < 4; mf++){
      short* dst = outb + ((size_t)b*NP + (size_t)py*P + pxg)*64 + mf*16 + kg*4;
      s16x4 o;
      #pragma unroll
      for (int j = 0; j < 4; j++) o[j] = f2bf(acc[mf][nf][j]);
      *(s16x4*)dst = o;
    }
  }

  // BN partial sums from fp32 acc (both pixels)
  #pragma unroll
  for (int mf = 0; mf < 4; mf++){
    #pragma unroll
    for (int j = 0; j < 4; j++){
      float a0 = acc[mf][0][j], a1 = acc[mf][1][j];
      float s = a0 + a1, q = a0*a0 + a1*a1;
      #pragma unroll
      for (int o = 1; o < 16; o <<= 1){
        s += __shfl_xor(s, o);
        q += __shfl_xor(q, o);
      }
      if (ln == 0){
        int ch = mf*16 + kg*4 + j;
        red_s[wid][ch] = s;
        red_q[wid][ch] = q;
      }
    }
  }
  __syncthreads();
  int blk = b*128 + tile;   // 0..511
  if (tid < 128){
    int ch = tid & 63;
    float v = (tid < 64)
      ? (red_s[0][ch]+red_s[1][ch]+red_s[2][ch]+red_s[3][ch])
      : (red_q[0][ch]+red_q[1][ch]+red_q[2][ch]+red_q[3][ch]);
    part[(size_t)tid*512 + blk] = v;
  }
}

// ---------------- BN finalize (512 partials per channel) ----------------
__global__ void bnfinal2_k(const float* __restrict__ part, const float* __restrict__ g,
                           const float* __restrict__ be, float* __restrict__ stats){
  int ch = blockIdx.x;
  int tid = threadIdx.x;
  float S = 0.f, Q = 0.f;
  for (int i = tid; i < 512; i += 256){
    S += part[(size_t)ch*512 + i];
    Q += part[(size_t)(64+ch)*512 + i];
  }
  __shared__ float rs[256], rq[256];
  rs[tid] = S; rq[tid] = Q;
  __syncthreads();
  for (int o = 128; o > 0; o >>= 1){
    if (tid < o){ rs[tid] += rs[tid+o]; rq[tid] += rq[tid+o]; }
    __syncthreads();
  }
  if (tid == 0){
    const float inv = 1.f/(float)(BATCH*NP);
    float mean = rs[0]*inv;
    float var = rq[0]*inv - mean*mean;
    float scale = rsqrtf(var + 1e-5f)*g[ch];
    stats[ch] = scale;
    stats[64+ch] = be[ch] - mean*scale;
  }
}

// ---------------- gates conv (128->256) MFMA + fused BN2 + LSTM ----------------
// Round-18 proven loop: M=256/block, tile 16x8 px; 36 chunks of 16KB (tap,cb),
// double-buffered A, single barrier per chunk, af[4]+bf[4] only (no spills).
__global__ __launch_bounds__(512, 4) void gates_mfma_k(
    const short* __restrict__ y2b, const float* __restrict__ stats,
    const short* __restrict__ hcl, const float* __restrict__ c0,
    const short* __restrict__ wA, const float* __restrict__ bg,
    float* __restrict__ outh, float* __restrict__ outc){
  extern __shared__ short lds[];
  short* bs = lds;                  // 180 px x 256B (swizzled) = 46080 B
  short* abuf = lds + 180*128;      // 2 x 8192 shorts (16 KB each)
  int tid = threadIdx.x;
  int tile = blockIdx.x, b = blockIdx.y;
  int tx0 = (tile & 7)*16, ty0 = (tile >> 3)*8;
  int lane = tid & 63, wid = tid >> 6;

  for (int e = tid; e < 180*16; e += 512){
    int cg = e & 15, p = e >> 4;
    int hr = p/18, wc = p - hr*18;
    int gy = ty0 + hr - 1, gx = tx0 + wc - 1;
    union { short s[8]; bf16x8 v; } u;
    if (((unsigned)gy < P) && ((unsigned)gx < P)){
      if (cg < 8){
        const short* src = y2b + ((size_t)(b*NP) + (size_t)gy*P + gx)*64 + cg*8;
        bf16x8 raw = *(const bf16x8*)src;
        int c = cg*8;
        #pragma unroll
        for (int j = 0; j < 8; j++){
          float v = fmaxf(bf2f(raw[j])*stats[c+j] + stats[64+c+j], 0.f);
          u.s[j] = f2bf(v);
        }
      } else {
        u.v = *(const bf16x8*)(hcl + ((size_t)(b*NP) + (size_t)gy*P + gx)*64 + (cg-8)*8);
      }
    } else {
      #pragma unroll
      for (int j = 0; j < 8; j++) u.s[j] = 0;
    }
    *(bf16x8*)((char*)bs + p*256 + ((cg*16) ^ ((p&7)<<4))) = u.v;
  }

  auto stageA = [&](int c, int bi){
    const short* g = wA + (size_t)c*8192;
    short* l = abuf + bi*8192;
    #pragma unroll
    for (int i = 0; i < 2; i++){
      int unit = wid*2 + i;
      __builtin_amdgcn_global_load_lds(
          (const __attribute__((address_space(1))) unsigned int*)(g + (size_t)(unit*64 + lane)*8),
          (__attribute__((address_space(3))) unsigned int*)(l + (size_t)unit*512),
          16, 0, 0);
    }
  };

  stageA(0, 0);
  stageA(1, 1);
  __syncthreads();   // B staged + chunks 0,1 landed

  int kg = lane >> 4, ln = lane & 15;
  int ct = wid >> 1, nh = wid & 1;
  f32x4 acc[4][4];
  #pragma unroll
  for (int mf = 0; mf < 4; mf++)
    #pragma unroll
    for (int rr = 0; rr < 4; rr++) acc[mf][rr] = (f32x4){0.f,0.f,0.f,0.f};

  for (int c = 0; c < 36; c++){
    int cur = c & 1;
    int tap = c >> 2, cb = c & 3;
    int ky = tap/3, kx = tap - ky*3;
    const short* al = abuf + cur*8192;
    bf16x8 af[4], bf[4];
    #pragma unroll
    for (int mf = 0; mf < 4; mf++)
      af[mf] = *(const bf16x8*)(al + (size_t)(ct*4 + mf)*512 + lane*8);
    #pragma unroll
    for (int rr = 0; rr < 4; rr++){
      int p = (nh*4 + rr + ky)*18 + ln + kx;
      bf[rr] = *(const bf16x8*)((const char*)bs + p*256 + (((cb*64) + kg*16) ^ ((p&7)<<4)));
    }
    asm volatile("s_waitcnt lgkmcnt(0)" ::: "memory");
    __builtin_amdgcn_sched_barrier(0);
    __builtin_amdgcn_s_setprio(1);
    #pragma unroll
    for (int rr = 0; rr < 4; rr++)
      #pragma unroll
      for (int mf = 0; mf < 4; mf++)
        acc[mf][rr] = __builtin_amdgcn_mfma_f32_16x16x32_bf16(af[mf], bf[rr], acc[mf][rr], 0, 0, 0);
    __builtin_amdgcn_s_setprio(0);
    asm volatile("s_waitcnt vmcnt(0)" ::: "memory");
    __builtin_amdgcn_sched_barrier(0);
    __builtin_amdgcn_s_barrier();
    __builtin_amdgcn_sched_barrier(0);
    if (c + 2 < 36) stageA(c + 2, cur);   // overlaps next iter's ds_read + MFMA
  }

  #pragma unroll
  for (int mf = 0; mf < 4; mf++){
    int ch = ct*16 + mf*4 + kg;
    float bi = bg[ch], bff = bg[64+ch], bo = bg[128+ch], bgv = bg[192+ch];
    #pragma unroll
    for (int rr = 0; rr < 4; rr++){
      int py = ty0 + nh*4 + rr, px = tx0 + ln;
      size_t pidx = ((size_t)(b*64 + ch))*NP + (size_t)py*P + px;
      f32x4 a = acc[mf][rr];
      float cv = sigmoidf_(a[1]+bff)*c0[pidx] + sigmoidf_(a[0]+bi)*tanhf_(a[3]+bgv);
      float hv = sigmoidf_(a[2]+bo)*tanhf_(cv);
      outh[pidx] = hv;
      outc[pidx] = cv;
    }
  }
}

extern "C" void kernel_launch(void* const* d_in, const int* in_sizes, int n_in,
                              void* d_out, int out_size, void* d_ws, size_t ws_size,
                              hipStream_t stream) {
  const float* x      = (const float*)d_in[0];
  const float* h0     = (const float*)d_in[1];
  const float* c0     = (const float*)d_in[2];
  const float* w_off1 = (const float*)d_in[3];
  const float* b_off1 = (const float*)d_in[4];
  const float* w1     = (const float*)d_in[5];
  const float* g1     = (const float*)d_in[6];
  const float* be1    = (const float*)d_in[7];
  const float* w_off2 = (const float*)d_in[8];
  const float* b_off2 = (const float*)d_in[9];
  const float* w2     = (const float*)d_in[10];
  const float* g2     = (const float*)d_in[11];
  const float* be2    = (const float*)d_in[12];
  const float* wg     = (const float*)d_in[13];
  const float* bg     = (const float*)d_in[14];

  float* ws     = (float*)d_ws;
  short* xph    = (short*)ws;                  // fp16, 2097152 shorts
  short* hcl    = (short*)(ws + 1048576);      // bf16, 4194304 shorts
  short* y1b    = (short*)(ws + 3145728);      // bf16, 4194304 shorts
  short* y2b    = (short*)(ws + 5242880);      // bf16, 4194304 shorts
  float* part   = ws + 7340032;                // 65536
  float* stats1 = ws + 7405568;                // 128
  float* stats2 = ws + 7405696;                // 128
  short* wA     = (short*)(ws + 7405824);      // 294912 shorts
  short* wd1T   = wA + 294912;                 // 18432
  short* wd2T   = wd1T + 18432;                // 36864
  short* woT1   = wd2T + 36864;                // 9216
  short* woT2   = woT1 + 9216;                 // 18432

  (void)hipFuncSetAttribute((const void*)gates_mfma_k,
                            hipFuncAttributeMaxDynamicSharedMemorySize, 78848);

  prep_k<<<dim3(256 + 1024 + 1476), dim3(256), 0, stream>>>(
      x, xph, h0, hcl, wg, w1, w2, w_off1, w_off2, wA, wd1T, wd2T, woT1, woT2);

  deform_fused_k<32,false,2><<<dim3(128, BATCH), dim3(256), 0, stream>>>(
      xph, stats1, b_off1, woT1, wd1T, y1b, part);
  bnfinal2_k<<<dim3(64), dim3(256), 0, stream>>>(part, g1, be1, stats1);

  deform_fused_k<64,true,1><<<dim3(128, BATCH), dim3(256), 0, stream>>>(
      y1b, stats1, b_off2, woT2, wd2T, y2b, part);
  bnfinal2_k<<<dim3(64), dim3(256), 0, stream>>>(part, g2, be2, stats2);

  float* outh = (float*)d_out;
  float* outc = outh + (size_t)BATCH*64*NP;
  gates_mfma_k<<<dim3(128, BATCH), dim3(512), 78848, stream>>>(
      y2b, stats2, hcl, c0, wA, bg, outh, outc);
}